// Round 9
// baseline (1353.872 us; speedup 1.0000x reference)
//
#include <hip/hip_runtime.h>
#include <math.h>

// Vanilla RNN: h_t = tanh(h_{t-1} @ wh + x_t @ wx + b), out = h_T  [B,1,H]
// B=256, T=2048, H=256, fp32 in/out.
//
// Round 8 = round 7 with the cvt_pkrtz type fixed (bit_cast __fp16x2->f16x2).
// Round 7 design: round 5 (911us, proven) + own-slice register fast-path:
//  - 256 blocks x 256 threads (4 waves, 1/SIMD). Step floor = 128 MFMA/CU
//    = 32/SIMD x 19.4cy = 620cy pipe; the rest is residue.
//  - The wave's own 32 h-cols (k-slice kt=2*wave) are rebuilt in registers
//    at the step tail via 8 __shfl + 4 v_cvt_pkrtz -> the first MFMA round
//    starts at cycle 0 after the barrier instead of waiting ~120cy for the
//    first ds_read_b128. wh fragments are loaded in per-wave ROTATED kt
//    order (kt_phys = (2*wave+i)&7) so all indices stay compile-time.
//  - Everything else identical to r5: serial chunk GEMM (wx frags resident),
//    replicated-row MFMA recurrence, k-split=2 (sets = logical i 0-3 / 4-7),
//    xw-seed prefetch, zero-seeded chains, 1 raw s_barrier/step.

typedef _Float16 f16;
typedef _Float16 f16x2 __attribute__((ext_vector_type(2)));
typedef _Float16 f16x4 __attribute__((ext_vector_type(4)));
typedef _Float16 f16x8 __attribute__((ext_vector_type(8)));
typedef __fp16   fp16v2 __attribute__((ext_vector_type(2)));
typedef float    f32x4 __attribute__((ext_vector_type(4)));

#define Bv 256
#define Tv 2048
#define Hv 256
#define TC 32
#define NCHUNK (Tv/TC)
#define XS_LD 264          // f16 row stride (528B -> 2-way banks, free)
#define XW_TS (TC+1)       // ts-dim pad: cq stride 33*16B=528B -> 2-way banks

#define LGKM_BARRIER() do { \
    asm volatile("s_waitcnt lgkmcnt(0)" ::: "memory"); \
    __builtin_amdgcn_s_barrier(); \
} while (0)

#define MFMA16(a, b, c) __builtin_amdgcn_mfma_f32_16x16x32_f16((a), (b), (c), 0, 0, 0)

__device__ __forceinline__ f16x4 cvt4(float4 v) {
    f16x4 r; r[0] = (f16)v.x; r[1] = (f16)v.y; r[2] = (f16)v.z; r[3] = (f16)v.w;
    return r;
}

__global__ __launch_bounds__(256, 1)
void HiddenLayer_704374636647_kernel(const float* __restrict__ x,
                                     const float* __restrict__ wx,
                                     const float* __restrict__ wh,
                                     const float* __restrict__ bias,
                                     float* __restrict__ out)
{
    __shared__ __align__(16) f16   xs16[TC][XS_LD];     // 16.9 KB
    __shared__ __align__(16) float xwc4[64][XW_TS][4];  // 33.8 KB
    __shared__ __align__(16) f16   hbuf[2][Hv];         //  1.0 KB

    const int  tid   = threadIdx.x;       // 0..255
    const int  wave  = tid >> 6;          // 0..3
    const int  lane  = tid & 63;
    const int  b     = blockIdx.x;
    const int  wbase = wave * 64;         // 64-col slice owned by wave
    const int  l15   = lane & 15;
    const int  grp   = lane >> 4;         // 0..3
    const int  cq    = wave * 16 + l15;   // xwc4 column-quad index
    const int  koff  = grp * 8;           // A-frag k-offset

    // element offsets (f16 units) into hbuf for logical kt slots 1..7
    // (slot 0 = own slice kt=2*wave, delivered via registers)
    const int oh1 = ((2 * wave + 1) & 7) * 32 + koff;
    const int oh2 = ((2 * wave + 2) & 7) * 32 + koff;
    const int oh3 = ((2 * wave + 3) & 7) * 32 + koff;
    const int oh4 = ((2 * wave + 4) & 7) * 32 + koff;
    const int oh5 = ((2 * wave + 5) & 7) * 32 + koff;
    const int oh6 = ((2 * wave + 6) & 7) * 32 + koff;
    const int oh7 = ((2 * wave + 7) & 7) * 32 + koff;

    const float* xb = x + (size_t)b * Tv * Hv;

    // ---- global x prefetch: 8 rows (wave + 4s) x 4 f32/lane
    float4 xr0, xr1, xr2, xr3, xr4, xr5, xr6, xr7;
#define LOADX(cc) do { const float* p_ = xb + ((size_t)(cc) * TC + wave) * Hv + lane * 4; \
    xr0 = *(const float4*)(p_);           xr1 = *(const float4*)(p_ +  4 * Hv); \
    xr2 = *(const float4*)(p_ +  8 * Hv); xr3 = *(const float4*)(p_ + 12 * Hv); \
    xr4 = *(const float4*)(p_ + 16 * Hv); xr5 = *(const float4*)(p_ + 20 * Hv); \
    xr6 = *(const float4*)(p_ + 24 * Hv); xr7 = *(const float4*)(p_ + 28 * Hv); } while (0)

    LOADX(0);

    // ---- weight B-frags: tile t covers col wbase + t*16 + l15
    //      wfh in ROTATED kt order: logical slot i -> physical kt (2*wave+i)&7
    //      wfx in natural kt order (GEMM indexes it with constexpr kt)
    f16x8 wfh[4][8];   // wh (recurrence)
    f16x8 wfx[4][8];   // wx (projection)
    #pragma unroll
    for (int t = 0; t < 4; ++t) {
        #pragma unroll
        for (int i = 0; i < 8; ++i) {
            const int ktp = (2 * wave + i) & 7;
            const float* ph = wh + (size_t)(ktp * 32 + koff) * Hv + wbase + t * 16 + l15;
            const float* pw = wx + (size_t)(i   * 32 + koff) * Hv + wbase + t * 16 + l15;
            f16x8 vh, vw;
            #pragma unroll
            for (int e = 0; e < 8; ++e) {
                vh[e] = (f16)ph[(size_t)e * Hv];
                vw[e] = (f16)pw[(size_t)e * Hv];
            }
            wfh[t][i] = vh;
            wfx[t][i] = vw;
        }
    }

    const float bc0 = bias[wbase + l15];
    const float bc1 = bias[wbase + 16 + l15];
    const float bc2 = bias[wbase + 32 + l15];
    const float bc3 = bias[wbase + 48 + l15];

    hbuf[0][tid] = (f16)0.0f;   // h_0 = 0 (256 threads cover 256)

    int   cur     = 0;
    float th_keep = 0.0f;
    f16x8 haO = {0,0,0,0,0,0,0,0};   // own-slice A-frag (h_0 = 0)

    #pragma unroll 1
    for (int c = 0; c < NCHUNK; ++c) {
        // ---- stage prefetched x (f32->f16): row wave+4s, cols lane*4..+3
        *(f16x4*)&xs16[wave     ][lane * 4] = cvt4(xr0);
        *(f16x4*)&xs16[wave +  4][lane * 4] = cvt4(xr1);
        *(f16x4*)&xs16[wave +  8][lane * 4] = cvt4(xr2);
        *(f16x4*)&xs16[wave + 12][lane * 4] = cvt4(xr3);
        *(f16x4*)&xs16[wave + 16][lane * 4] = cvt4(xr4);
        *(f16x4*)&xs16[wave + 20][lane * 4] = cvt4(xr5);
        *(f16x4*)&xs16[wave + 24][lane * 4] = cvt4(xr6);
        *(f16x4*)&xs16[wave + 28][lane * 4] = cvt4(xr7);

        if (c + 1 < NCHUNK) LOADX(c + 1);   // in flight across GEMM + scan

        LGKM_BARRIER();   // xs16 visible (and hbuf zeros / xwc4 free)

        // ---- chunk GEMM: xwc4 = xs16 @ wx + bias (per wave: its 64 cols)
        {
            f32x4 gA0 = {bc0,bc0,bc0,bc0}, gA1 = {bc1,bc1,bc1,bc1};
            f32x4 gA2 = {bc2,bc2,bc2,bc2}, gA3 = {bc3,bc3,bc3,bc3};
            f32x4 gB0 = gA0, gB1 = gA1, gB2 = gA2, gB3 = gA3;
            #pragma unroll
            for (int kt = 0; kt < 8; ++kt) {
                f16x8 u0 = *(const f16x8*)&xs16[l15     ][kt * 32 + koff];
                f16x8 u1 = *(const f16x8*)&xs16[l15 + 16][kt * 32 + koff];
                gA0 = MFMA16(u0, wfx[0][kt], gA0);
                gA1 = MFMA16(u0, wfx[1][kt], gA1);
                gA2 = MFMA16(u0, wfx[2][kt], gA2);
                gA3 = MFMA16(u0, wfx[3][kt], gA3);
                gB0 = MFMA16(u1, wfx[0][kt], gB0);
                gB1 = MFMA16(u1, wfx[1][kt], gB1);
                gB2 = MFMA16(u1, wfx[2][kt], gB2);
                gB3 = MFMA16(u1, wfx[3][kt], gB3);
            }
            // D: row(ts) = grp*4 + r, col = l15 -> write [cq][ts] as 4-col quad
            #pragma unroll
            for (int r = 0; r < 4; ++r) {
                f32x4 v = {gA0[r], gA1[r], gA2[r], gA3[r]};
                *(f32x4*)&xwc4[cq][grp * 4 + r][0] = v;
                f32x4 w = {gB0[r], gB1[r], gB2[r], gB3[r]};
                *(f32x4*)&xwc4[cq][16 + grp * 4 + r][0] = w;
            }
        }

        LGKM_BARRIER();   // xwc4 visible

        // ---- scan TC steps, 1 barrier each (double-buffered h)
        f32x4 xwn = *(const f32x4*)&xwc4[cq][0][0];
        for (int ts = 0; ts < TC; ++ts) {
            const f16* hp = &hbuf[cur][0];
            // 7 broadcast ds_read_b128 (logical slots 1..7; slot 0 = haO regs)
            f16x8 h1 = *(const f16x8*)(hp + oh1);
            f16x8 h2 = *(const f16x8*)(hp + oh2);
            f16x8 h3 = *(const f16x8*)(hp + oh3);
            f16x8 h4 = *(const f16x8*)(hp + oh4);
            f16x8 h5 = *(const f16x8*)(hp + oh5);
            f16x8 h6 = *(const f16x8*)(hp + oh6);
            f16x8 h7 = *(const f16x8*)(hp + oh7);

            // this step's xw select (off critical path), then prefetch next
            float x01   = (grp & 1) ? xwn[1] : xwn[0];
            float x23   = (grp & 1) ? xwn[3] : xwn[2];
            float xwsel = (grp & 2) ? x23 : x01;
            const int tsn = (ts + 1 < TC) ? ts + 1 : ts;
            xwn = *(const f32x4*)&xwc4[cq][tsn][0];

            // chains: set A = logical slots 0-3 (starts on haO, in regs),
            //         set B = logical slots 4-7. Zero-seeded, combine at end.
            const f32x4 z = {0.f, 0.f, 0.f, 0.f};
            f32x4 a0A = MFMA16(haO, wfh[0][0], z);
            f32x4 a1A = MFMA16(haO, wfh[1][0], z);
            f32x4 a2A = MFMA16(haO, wfh[2][0], z);
            f32x4 a3A = MFMA16(haO, wfh[3][0], z);

            a0A = MFMA16(h1, wfh[0][1], a0A);
            a1A = MFMA16(h1, wfh[1][1], a1A);
            a2A = MFMA16(h1, wfh[2][1], a2A);
            a3A = MFMA16(h1, wfh[3][1], a3A);

            f32x4 a0B = MFMA16(h4, wfh[0][4], z);
            f32x4 a1B = MFMA16(h4, wfh[1][4], z);
            f32x4 a2B = MFMA16(h4, wfh[2][4], z);
            f32x4 a3B = MFMA16(h4, wfh[3][4], z);

            a0A = MFMA16(h2, wfh[0][2], a0A);
            a1A = MFMA16(h2, wfh[1][2], a1A);
            a2A = MFMA16(h2, wfh[2][2], a2A);
            a3A = MFMA16(h2, wfh[3][2], a3A);

            a0B = MFMA16(h5, wfh[0][5], a0B);
            a1B = MFMA16(h5, wfh[1][5], a1B);
            a2B = MFMA16(h5, wfh[2][5], a2B);
            a3B = MFMA16(h5, wfh[3][5], a3B);

            a0A = MFMA16(h3, wfh[0][3], a0A);
            a1A = MFMA16(h3, wfh[1][3], a1A);
            a2A = MFMA16(h3, wfh[2][3], a2A);
            a3A = MFMA16(h3, wfh[3][3], a3A);

            a0B = MFMA16(h6, wfh[0][6], a0B);
            a1B = MFMA16(h6, wfh[1][6], a1B);
            a2B = MFMA16(h6, wfh[2][6], a2B);
            a3B = MFMA16(h6, wfh[3][6], a3B);

            a0B = MFMA16(h7, wfh[0][7], a0B);
            a1B = MFMA16(h7, wfh[1][7], a1B);
            a2B = MFMA16(h7, wfh[2][7], a2B);
            a3B = MFMA16(h7, wfh[3][7], a3B);

            // this lane owns tile (grp): col = wbase + grp*16 + l15 = wbase+lane
            float sA01 = (grp & 1) ? a1A[0] : a0A[0];
            float sA23 = (grp & 1) ? a3A[0] : a2A[0];
            float sA   = (grp & 2) ? sA23 : sA01;
            float sB01 = (grp & 1) ? a1B[0] : a0B[0];
            float sB23 = (grp & 1) ? a3B[0] : a2B[0];
            float sB   = (grp & 2) ? sB23 : sB01;
            float s    = (sA + sB) + xwsel;

            float e   = __expf(2.f * s);
            float th  = 1.f - __fdividef(2.f, e + 1.f);
            th_keep = th;
            hbuf[cur ^ 1][wbase + lane] = (f16)th;

            // rebuild own-slice A-frag in regs for the NEXT step:
            // haO[e] = h_next[2*wave*32 + koff + e] = th of lane (koff+e)
            {
                float s0 = __shfl(th, koff + 0);
                float s1 = __shfl(th, koff + 1);
                float s2 = __shfl(th, koff + 2);
                float s3 = __shfl(th, koff + 3);
                float s4 = __shfl(th, koff + 4);
                float s5 = __shfl(th, koff + 5);
                float s6 = __shfl(th, koff + 6);
                float s7 = __shfl(th, koff + 7);
#if __has_builtin(__builtin_amdgcn_cvt_pkrtz)
                f16x2 p0 = __builtin_bit_cast(f16x2, __builtin_amdgcn_cvt_pkrtz(s0, s1));
                f16x2 p1 = __builtin_bit_cast(f16x2, __builtin_amdgcn_cvt_pkrtz(s2, s3));
                f16x2 p2 = __builtin_bit_cast(f16x2, __builtin_amdgcn_cvt_pkrtz(s4, s5));
                f16x2 p3 = __builtin_bit_cast(f16x2, __builtin_amdgcn_cvt_pkrtz(s6, s7));
                f16x4 q0 = __builtin_shufflevector(p0, p1, 0, 1, 2, 3);
                f16x4 q1 = __builtin_shufflevector(p2, p3, 0, 1, 2, 3);
                haO = __builtin_shufflevector(q0, q1, 0, 1, 2, 3, 4, 5, 6, 7);
#else
                haO[0] = (f16)s0; haO[1] = (f16)s1; haO[2] = (f16)s2; haO[3] = (f16)s3;
                haO[4] = (f16)s4; haO[5] = (f16)s5; haO[6] = (f16)s6; haO[7] = (f16)s7;
#endif
            }

            LGKM_BARRIER();
            cur ^= 1;
        }
    }

    // th_keep's col = wbase + lane -> coalesced store
    out[(size_t)b * Hv + wbase + lane] = th_keep;
}

extern "C" void kernel_launch(void* const* d_in, const int* in_sizes, int n_in,
                              void* d_out, int out_size, void* d_ws, size_t ws_size,
                              hipStream_t stream) {
    const float* x    = (const float*)d_in[0];   // [B,T,H]
    const float* wx   = (const float*)d_in[1];   // [H,H]
    const float* wh   = (const float*)d_in[2];   // [H,H]
    const float* bias = (const float*)d_in[3];   // [1,H]
    float* out = (float*)d_out;                  // [B,1,H]

    hipLaunchKernelGGL(HiddenLayer_704374636647_kernel,
                       dim3(Bv), dim3(256), 0, stream,
                       x, wx, wh, bias, out);
}

// Round 10
// 1162.140 us; speedup vs baseline: 1.1650x; 1.1650x over previous
//
#include <hip/hip_runtime.h>
#include <math.h>

// Vanilla RNN: h_t = tanh(h_{t-1} @ wh + x_t @ wx + b), out = h_T  [B,1,H]
// B=256, T=2048, H=256, fp32 in/out.
//
// Round 9 = round 5 (911us, proven) + pre-barrier own-slice LDS pre-read:
//  - 256 blocks x 256 threads (4 waves, 1/SIMD). Pipe floor: 32 MFMA/SIMD
//    x 19.4cy = 620cy/step; residue was ~450cy, dominated by the ~120cy
//    post-barrier ds_read fill.
//  - NEW: the 2 h-slices wave w needs FIRST (kt=2w,2w+1 = cols [64w,64w+64))
//    are written by wave w itself. LDS ops are in-order per wave, so the
//    wave pre-reads those two fragments right after its own ds_write,
//    BEFORE the barrier -> chains start on ready registers at barrier-exit
//    (saves ~120cy fill; costs ~24cy extra lgkm drain). This is r7's goal
//    done via wave-local LDS RAW instead of ds_bpermute (r8's mistake:
//    __shfl IS a DS op).
//  - wfh in per-wave ROTATED slot order (slot i -> kt=(2w+i)&7), chains
//    A = slots 0-3 (slots 0,1 pre-read), B = slots 4-7. All indices static.
//  - xw folded into chain-A's C-seed (select runs pre-MFMA, hidden).
//  - tsn clamp removed (XW_TS=33 pad row; value discarded at chunk end).
//  - GEMM->scan boundary barrier removed (xwc4[cq] is wave-local RAW).

typedef _Float16 f16;
typedef _Float16 f16x4 __attribute__((ext_vector_type(4)));
typedef _Float16 f16x8 __attribute__((ext_vector_type(8)));
typedef float    f32x4 __attribute__((ext_vector_type(4)));

#define Bv 256
#define Tv 2048
#define Hv 256
#define TC 32
#define NCHUNK (Tv/TC)
#define XS_LD 264          // f16 row stride (528B -> 2-way banks, free)
#define XW_TS (TC+1)       // ts-dim pad: row ts+1 always readable (incl. ts=31)

#define LGKM_BARRIER() do { \
    asm volatile("s_waitcnt lgkmcnt(0)" ::: "memory"); \
    __builtin_amdgcn_s_barrier(); \
} while (0)

#define MFMA16(a, b, c) __builtin_amdgcn_mfma_f32_16x16x32_f16((a), (b), (c), 0, 0, 0)

__device__ __forceinline__ f16x4 cvt4(float4 v) {
    f16x4 r; r[0] = (f16)v.x; r[1] = (f16)v.y; r[2] = (f16)v.z; r[3] = (f16)v.w;
    return r;
}

__global__ __launch_bounds__(256, 1)
void HiddenLayer_704374636647_kernel(const float* __restrict__ x,
                                     const float* __restrict__ wx,
                                     const float* __restrict__ wh,
                                     const float* __restrict__ bias,
                                     float* __restrict__ out)
{
    __shared__ __align__(16) f16   xs16[TC][XS_LD];     // 16.9 KB
    __shared__ __align__(16) float xwc4[64][XW_TS][4];  // 33.8 KB
    __shared__ __align__(16) f16   hbuf[2][Hv];         //  1.0 KB

    const int  tid   = threadIdx.x;       // 0..255
    const int  wave  = tid >> 6;          // 0..3
    const int  lane  = tid & 63;
    const int  b     = blockIdx.x;
    const int  wbase = wave * 64;         // 64-col slice owned by wave
    const int  l15   = lane & 15;
    const int  grp   = lane >> 4;         // 0..3
    const int  cq    = wave * 16 + l15;   // xwc4 column-quad index
    const int  koff  = grp * 8;           // A-frag k-offset

    // own-slice element offsets (pre-read targets): slots 0,1 = kt 2w, 2w+1
    const int own0 = wave * 64 + koff;    // slot 0
    const int own1 = own0 + 32;           // slot 1
    // post-barrier read offsets for slots 2..7 (rotated: slot i -> kt (2w+i)&7)
    const int oh2 = ((2 * wave + 2) & 7) * 32 + koff;
    const int oh3 = ((2 * wave + 3) & 7) * 32 + koff;
    const int oh4 = ((2 * wave + 4) & 7) * 32 + koff;
    const int oh5 = ((2 * wave + 5) & 7) * 32 + koff;
    const int oh6 = ((2 * wave + 6) & 7) * 32 + koff;
    const int oh7 = ((2 * wave + 7) & 7) * 32 + koff;

    const float* xb = x + (size_t)b * Tv * Hv;

    // ---- global x prefetch: 8 rows (wave + 4s) x 4 f32/lane
    float4 xr0, xr1, xr2, xr3, xr4, xr5, xr6, xr7;
#define LOADX(cc) do { const float* p_ = xb + ((size_t)(cc) * TC + wave) * Hv + lane * 4; \
    xr0 = *(const float4*)(p_);           xr1 = *(const float4*)(p_ +  4 * Hv); \
    xr2 = *(const float4*)(p_ +  8 * Hv); xr3 = *(const float4*)(p_ + 12 * Hv); \
    xr4 = *(const float4*)(p_ + 16 * Hv); xr5 = *(const float4*)(p_ + 20 * Hv); \
    xr6 = *(const float4*)(p_ + 24 * Hv); xr7 = *(const float4*)(p_ + 28 * Hv); } while (0)

    LOADX(0);

    // ---- weight B-frags: tile t covers col wbase + t*16 + l15
    //      wfh ROTATED: slot i -> physical kt (2*wave+i)&7 ; wfx natural order
    f16x8 wfh[4][8];   // wh (recurrence)
    f16x8 wfx[4][8];   // wx (projection)
    #pragma unroll
    for (int t = 0; t < 4; ++t) {
        #pragma unroll
        for (int i = 0; i < 8; ++i) {
            const int ktp = (2 * wave + i) & 7;
            const float* ph = wh + (size_t)(ktp * 32 + koff) * Hv + wbase + t * 16 + l15;
            const float* pw = wx + (size_t)(i   * 32 + koff) * Hv + wbase + t * 16 + l15;
            f16x8 vh, vw;
            #pragma unroll
            for (int e = 0; e < 8; ++e) {
                vh[e] = (f16)ph[(size_t)e * Hv];
                vw[e] = (f16)pw[(size_t)e * Hv];
            }
            wfh[t][i] = vh;
            wfx[t][i] = vw;
        }
    }

    const float bc0 = bias[wbase + l15];
    const float bc1 = bias[wbase + 16 + l15];
    const float bc2 = bias[wbase + 32 + l15];
    const float bc3 = bias[wbase + 48 + l15];

    hbuf[0][tid] = (f16)0.0f;   // h_0 = 0 (256 threads cover 256)

    int   cur     = 0;
    float th_keep = 0.0f;
    f16x8 hpre0 = {0,0,0,0,0,0,0,0};   // slot-0 frag of h_0 (= zeros)
    f16x8 hpre1 = {0,0,0,0,0,0,0,0};   // slot-1 frag of h_0

    #pragma unroll 1
    for (int c = 0; c < NCHUNK; ++c) {
        // ---- stage prefetched x (f32->f16): row wave+4s, cols lane*4..+3
        *(f16x4*)&xs16[wave     ][lane * 4] = cvt4(xr0);
        *(f16x4*)&xs16[wave +  4][lane * 4] = cvt4(xr1);
        *(f16x4*)&xs16[wave +  8][lane * 4] = cvt4(xr2);
        *(f16x4*)&xs16[wave + 12][lane * 4] = cvt4(xr3);
        *(f16x4*)&xs16[wave + 16][lane * 4] = cvt4(xr4);
        *(f16x4*)&xs16[wave + 20][lane * 4] = cvt4(xr5);
        *(f16x4*)&xs16[wave + 24][lane * 4] = cvt4(xr6);
        *(f16x4*)&xs16[wave + 28][lane * 4] = cvt4(xr7);

        if (c + 1 < NCHUNK) LOADX(c + 1);   // in flight across GEMM + scan

        LGKM_BARRIER();   // xs16 visible (and hbuf zeros at c==0)

        // ---- chunk GEMM: xwc4 = xs16 @ wx + bias (per wave: its 64 cols)
        {
            f32x4 gA0 = {bc0,bc0,bc0,bc0}, gA1 = {bc1,bc1,bc1,bc1};
            f32x4 gA2 = {bc2,bc2,bc2,bc2}, gA3 = {bc3,bc3,bc3,bc3};
            f32x4 gB0 = gA0, gB1 = gA1, gB2 = gA2, gB3 = gA3;
            #pragma unroll
            for (int kt = 0; kt < 8; ++kt) {
                f16x8 u0 = *(const f16x8*)&xs16[l15     ][kt * 32 + koff];
                f16x8 u1 = *(const f16x8*)&xs16[l15 + 16][kt * 32 + koff];
                gA0 = MFMA16(u0, wfx[0][kt], gA0);
                gA1 = MFMA16(u0, wfx[1][kt], gA1);
                gA2 = MFMA16(u0, wfx[2][kt], gA2);
                gA3 = MFMA16(u0, wfx[3][kt], gA3);
                gB0 = MFMA16(u1, wfx[0][kt], gB0);
                gB1 = MFMA16(u1, wfx[1][kt], gB1);
                gB2 = MFMA16(u1, wfx[2][kt], gB2);
                gB3 = MFMA16(u1, wfx[3][kt], gB3);
            }
            // D: row(ts) = grp*4 + r, col = l15 -> write [cq][ts] as 4-col quad
            #pragma unroll
            for (int r = 0; r < 4; ++r) {
                f32x4 v = {gA0[r], gA1[r], gA2[r], gA3[r]};
                *(f32x4*)&xwc4[cq][grp * 4 + r][0] = v;
                f32x4 w = {gB0[r], gB1[r], gB2[r], gB3[r]};
                *(f32x4*)&xwc4[cq][16 + grp * 4 + r][0] = w;
            }
        }

        // NO barrier here: xwc4[cq][*] is written and read by the SAME wave
        // (lane l15 groups); DS is in-order per wave -> RAW is safe.

        // ---- scan TC steps, 1 barrier each (double-buffered h)
        f32x4 xwn = *(const f32x4*)&xwc4[cq][0][0];
        for (int ts = 0; ts < TC; ++ts) {
            const f16* hp = &hbuf[cur][0];
            // post-barrier: 6 broadcast ds_read_b128 (slots 2..7)
            f16x8 h2 = *(const f16x8*)(hp + oh2);
            f16x8 h3 = *(const f16x8*)(hp + oh3);
            f16x8 h4 = *(const f16x8*)(hp + oh4);
            f16x8 h5 = *(const f16x8*)(hp + oh5);
            f16x8 h6 = *(const f16x8*)(hp + oh6);
            f16x8 h7 = *(const f16x8*)(hp + oh7);

            // xw select for THIS step from last step's prefetched xwn
            // (pre-MFMA, off the critical path), then prefetch next row
            float x01   = (grp & 1) ? xwn[1] : xwn[0];
            float x23   = (grp & 1) ? xwn[3] : xwn[2];
            float xwsel = (grp & 2) ? x23 : x01;
            xwn = *(const f32x4*)&xwc4[cq][ts + 1][0];   // row 32 = pad, discarded

            // chains: A = slots 0-3 (slots 0,1 already in regs -> pipe starts
            // at barrier-exit), xw folded into A's C-seed (reg0 only matters);
            // B = slots 4-7, zero-seeded.
            const f32x4 sd = {xwsel, 0.f, 0.f, 0.f};
            const f32x4 z  = {0.f, 0.f, 0.f, 0.f};
            f32x4 a0A = MFMA16(hpre0, wfh[0][0], sd);
            f32x4 a1A = MFMA16(hpre0, wfh[1][0], sd);
            f32x4 a2A = MFMA16(hpre0, wfh[2][0], sd);
            f32x4 a3A = MFMA16(hpre0, wfh[3][0], sd);

            a0A = MFMA16(hpre1, wfh[0][1], a0A);
            a1A = MFMA16(hpre1, wfh[1][1], a1A);
            a2A = MFMA16(hpre1, wfh[2][1], a2A);
            a3A = MFMA16(hpre1, wfh[3][1], a3A);

            f32x4 a0B = MFMA16(h4, wfh[0][4], z);
            f32x4 a1B = MFMA16(h4, wfh[1][4], z);
            f32x4 a2B = MFMA16(h4, wfh[2][4], z);
            f32x4 a3B = MFMA16(h4, wfh[3][4], z);

            a0A = MFMA16(h2, wfh[0][2], a0A);
            a1A = MFMA16(h2, wfh[1][2], a1A);
            a2A = MFMA16(h2, wfh[2][2], a2A);
            a3A = MFMA16(h2, wfh[3][2], a3A);

            a0B = MFMA16(h5, wfh[0][5], a0B);
            a1B = MFMA16(h5, wfh[1][5], a1B);
            a2B = MFMA16(h5, wfh[2][5], a2B);
            a3B = MFMA16(h5, wfh[3][5], a3B);

            a0A = MFMA16(h3, wfh[0][3], a0A);
            a1A = MFMA16(h3, wfh[1][3], a1A);
            a2A = MFMA16(h3, wfh[2][3], a2A);
            a3A = MFMA16(h3, wfh[3][3], a3A);

            a0B = MFMA16(h6, wfh[0][6], a0B);
            a1B = MFMA16(h6, wfh[1][6], a1B);
            a2B = MFMA16(h6, wfh[2][6], a2B);
            a3B = MFMA16(h6, wfh[3][6], a3B);

            a0B = MFMA16(h7, wfh[0][7], a0B);
            a1B = MFMA16(h7, wfh[1][7], a1B);
            a2B = MFMA16(h7, wfh[2][7], a2B);
            a3B = MFMA16(h7, wfh[3][7], a3B);

            // this lane owns tile (grp): col = wbase + grp*16 + l15 = wbase+lane
            float sA01 = (grp & 1) ? a1A[0] : a0A[0];
            float sA23 = (grp & 1) ? a3A[0] : a2A[0];
            float sA   = (grp & 2) ? sA23 : sA01;   // includes xw seed
            float sB01 = (grp & 1) ? a1B[0] : a0B[0];
            float sB23 = (grp & 1) ? a3B[0] : a2B[0];
            float sB   = (grp & 2) ? sB23 : sB01;
            float s    = sA + sB;

            float e   = __expf(2.f * s);
            float th  = 1.f - __fdividef(2.f, e + 1.f);
            th_keep = th;
            f16* hnx = &hbuf[cur ^ 1][0];
            hnx[wbase + lane] = (f16)th;

            // pre-barrier pre-read of the wave's OWN slices for the next step
            // (cols [64w,64w+64) were just written by THIS wave; in-order DS
            // per wave makes this RAW-safe before the barrier).
            hpre0 = *(const f16x8*)(hnx + own0);
            hpre1 = *(const f16x8*)(hnx + own1);

            LGKM_BARRIER();
            cur ^= 1;
        }
    }

    // th_keep's col = wbase + lane -> coalesced store
    out[(size_t)b * Hv + wbase + lane] = th_keep;
}

extern "C" void kernel_launch(void* const* d_in, const int* in_sizes, int n_in,
                              void* d_out, int out_size, void* d_ws, size_t ws_size,
                              hipStream_t stream) {
    const float* x    = (const float*)d_in[0];   // [B,T,H]
    const float* wx   = (const float*)d_in[1];   // [H,H]
    const float* wh   = (const float*)d_in[2];   // [H,H]
    const float* bias = (const float*)d_in[3];   // [1,H]
    float* out = (float*)d_out;                  // [B,1,H]

    hipLaunchKernelGGL(HiddenLayer_704374636647_kernel,
                       dim3(Bv), dim3(256), 0, stream,
                       x, wx, wh, bias, out);
}

// Round 11
// 1128.165 us; speedup vs baseline: 1.2001x; 1.0301x over previous
//
#include <hip/hip_runtime.h>
#include <math.h>

// Vanilla RNN: h_t = tanh(h_{t-1} @ wh + x_t @ wx + b), out = h_T  [B,1,H]
// B=256, T=2048, H=256, fp32 in/out.
//
// Round 10 = round 5 (911us, proven) + own-slice pre-read with COUNTED drain:
//  - r9's pre-read was right but its lgkmcnt(0) serialized write->read into
//    the pre-barrier tail (+250cy). Fix: the barrier only needs the WRITE
//    visible; the 2 pre-reads are wave-local and may stay in flight ACROSS
//    the barrier. LDS completes in-order per wave, so
//    s_waitcnt lgkmcnt(2) (leaves the 2 newest = the pre-reads pending)
//    guarantees the write is done -> barrier -> pre-read latency overlaps
//    the barrier wait; chain A starts on registers at barrier exit.
//  - wfh in per-wave ROTATED slot order (slot i -> kt=(2w+i)&7): slots 0,1
//    are the wave's own cols [64w,64w+64), written by itself, pre-readable.
//  - Everything else EXACTLY r5: serial chunk GEMM (barrier kept), xw added
//    at combine, zero-seeded k-split chains, 1 barrier/step.

typedef _Float16 f16;
typedef _Float16 f16x4 __attribute__((ext_vector_type(4)));
typedef _Float16 f16x8 __attribute__((ext_vector_type(8)));
typedef float    f32x4 __attribute__((ext_vector_type(4)));

#define Bv 256
#define Tv 2048
#define Hv 256
#define TC 32
#define NCHUNK (Tv/TC)
#define XS_LD 264          // f16 row stride (528B -> 2-way banks, free)
#define XW_TS (TC+1)       // ts-dim pad: row ts+1 always readable (incl. ts=31)

#define LGKM_BARRIER() do { \
    asm volatile("s_waitcnt lgkmcnt(0)" ::: "memory"); \
    __builtin_amdgcn_s_barrier(); \
} while (0)

// scan-step barrier: leave the 2 own-slice pre-reads in flight
#define SCAN_BARRIER() do { \
    asm volatile("s_waitcnt lgkmcnt(2)" ::: "memory"); \
    __builtin_amdgcn_s_barrier(); \
} while (0)

#define MFMA16(a, b, c) __builtin_amdgcn_mfma_f32_16x16x32_f16((a), (b), (c), 0, 0, 0)

__device__ __forceinline__ f16x4 cvt4(float4 v) {
    f16x4 r; r[0] = (f16)v.x; r[1] = (f16)v.y; r[2] = (f16)v.z; r[3] = (f16)v.w;
    return r;
}

__global__ __launch_bounds__(256, 1)
void HiddenLayer_704374636647_kernel(const float* __restrict__ x,
                                     const float* __restrict__ wx,
                                     const float* __restrict__ wh,
                                     const float* __restrict__ bias,
                                     float* __restrict__ out)
{
    __shared__ __align__(16) f16   xs16[TC][XS_LD];     // 16.9 KB
    __shared__ __align__(16) float xwc4[64][XW_TS][4];  // 33.8 KB
    __shared__ __align__(16) f16   hbuf[2][Hv];         //  1.0 KB

    const int  tid   = threadIdx.x;       // 0..255
    const int  wave  = tid >> 6;          // 0..3
    const int  lane  = tid & 63;
    const int  b     = blockIdx.x;
    const int  wbase = wave * 64;         // 64-col slice owned by wave
    const int  l15   = lane & 15;
    const int  grp   = lane >> 4;         // 0..3
    const int  cq    = wave * 16 + l15;   // xwc4 column-quad index
    const int  koff  = grp * 8;           // A-frag k-offset

    // own-slice offsets (pre-read): slots 0,1 = kt 2w, 2w+1 (cols 64w..64w+64)
    const int own0 = wave * 64 + koff;
    const int own1 = own0 + 32;
    // post-barrier read offsets, slots 2..7 (rotated: slot i -> kt (2w+i)&7)
    const int oh2 = ((2 * wave + 2) & 7) * 32 + koff;
    const int oh3 = ((2 * wave + 3) & 7) * 32 + koff;
    const int oh4 = ((2 * wave + 4) & 7) * 32 + koff;
    const int oh5 = ((2 * wave + 5) & 7) * 32 + koff;
    const int oh6 = ((2 * wave + 6) & 7) * 32 + koff;
    const int oh7 = ((2 * wave + 7) & 7) * 32 + koff;

    const float* xb = x + (size_t)b * Tv * Hv;

    // ---- global x prefetch: 8 rows (wave + 4s) x 4 f32/lane
    float4 xr0, xr1, xr2, xr3, xr4, xr5, xr6, xr7;
#define LOADX(cc) do { const float* p_ = xb + ((size_t)(cc) * TC + wave) * Hv + lane * 4; \
    xr0 = *(const float4*)(p_);           xr1 = *(const float4*)(p_ +  4 * Hv); \
    xr2 = *(const float4*)(p_ +  8 * Hv); xr3 = *(const float4*)(p_ + 12 * Hv); \
    xr4 = *(const float4*)(p_ + 16 * Hv); xr5 = *(const float4*)(p_ + 20 * Hv); \
    xr6 = *(const float4*)(p_ + 24 * Hv); xr7 = *(const float4*)(p_ + 28 * Hv); } while (0)

    LOADX(0);

    // ---- weight B-frags: tile t covers col wbase + t*16 + l15
    //      wfh ROTATED: slot i -> physical kt (2*wave+i)&7 ; wfx natural order
    f16x8 wfh[4][8];   // wh (recurrence)
    f16x8 wfx[4][8];   // wx (projection)
    #pragma unroll
    for (int t = 0; t < 4; ++t) {
        #pragma unroll
        for (int i = 0; i < 8; ++i) {
            const int ktp = (2 * wave + i) & 7;
            const float* ph = wh + (size_t)(ktp * 32 + koff) * Hv + wbase + t * 16 + l15;
            const float* pw = wx + (size_t)(i   * 32 + koff) * Hv + wbase + t * 16 + l15;
            f16x8 vh, vw;
            #pragma unroll
            for (int e = 0; e < 8; ++e) {
                vh[e] = (f16)ph[(size_t)e * Hv];
                vw[e] = (f16)pw[(size_t)e * Hv];
            }
            wfh[t][i] = vh;
            wfx[t][i] = vw;
        }
    }

    const float bc0 = bias[wbase + l15];
    const float bc1 = bias[wbase + 16 + l15];
    const float bc2 = bias[wbase + 32 + l15];
    const float bc3 = bias[wbase + 48 + l15];

    hbuf[0][tid] = (f16)0.0f;   // h_0 = 0 (256 threads cover 256)

    int   cur     = 0;
    float th_keep = 0.0f;
    f16x8 hpre0 = {0,0,0,0,0,0,0,0};   // slot-0 frag of h_0 (= zeros)
    f16x8 hpre1 = {0,0,0,0,0,0,0,0};   // slot-1 frag of h_0

    #pragma unroll 1
    for (int c = 0; c < NCHUNK; ++c) {
        // ---- stage prefetched x (f32->f16): row wave+4s, cols lane*4..+3
        *(f16x4*)&xs16[wave     ][lane * 4] = cvt4(xr0);
        *(f16x4*)&xs16[wave +  4][lane * 4] = cvt4(xr1);
        *(f16x4*)&xs16[wave +  8][lane * 4] = cvt4(xr2);
        *(f16x4*)&xs16[wave + 12][lane * 4] = cvt4(xr3);
        *(f16x4*)&xs16[wave + 16][lane * 4] = cvt4(xr4);
        *(f16x4*)&xs16[wave + 20][lane * 4] = cvt4(xr5);
        *(f16x4*)&xs16[wave + 24][lane * 4] = cvt4(xr6);
        *(f16x4*)&xs16[wave + 28][lane * 4] = cvt4(xr7);

        if (c + 1 < NCHUNK) LOADX(c + 1);   // in flight across GEMM + scan

        LGKM_BARRIER();   // xs16 visible (also drains prev-chunk pre-reads)

        // ---- chunk GEMM: xwc4 = xs16 @ wx + bias (per wave: its 64 cols)
        {
            f32x4 gA0 = {bc0,bc0,bc0,bc0}, gA1 = {bc1,bc1,bc1,bc1};
            f32x4 gA2 = {bc2,bc2,bc2,bc2}, gA3 = {bc3,bc3,bc3,bc3};
            f32x4 gB0 = gA0, gB1 = gA1, gB2 = gA2, gB3 = gA3;
            #pragma unroll
            for (int kt = 0; kt < 8; ++kt) {
                f16x8 u0 = *(const f16x8*)&xs16[l15     ][kt * 32 + koff];
                f16x8 u1 = *(const f16x8*)&xs16[l15 + 16][kt * 32 + koff];
                gA0 = MFMA16(u0, wfx[0][kt], gA0);
                gA1 = MFMA16(u0, wfx[1][kt], gA1);
                gA2 = MFMA16(u0, wfx[2][kt], gA2);
                gA3 = MFMA16(u0, wfx[3][kt], gA3);
                gB0 = MFMA16(u1, wfx[0][kt], gB0);
                gB1 = MFMA16(u1, wfx[1][kt], gB1);
                gB2 = MFMA16(u1, wfx[2][kt], gB2);
                gB3 = MFMA16(u1, wfx[3][kt], gB3);
            }
            // D: row(ts) = grp*4 + r, col = l15 -> write [cq][ts] as 4-col quad
            #pragma unroll
            for (int r = 0; r < 4; ++r) {
                f32x4 v = {gA0[r], gA1[r], gA2[r], gA3[r]};
                *(f32x4*)&xwc4[cq][grp * 4 + r][0] = v;
                f32x4 w = {gB0[r], gB1[r], gB2[r], gB3[r]};
                *(f32x4*)&xwc4[cq][16 + grp * 4 + r][0] = w;
            }
        }

        LGKM_BARRIER();   // xwc4 visible (as in r5)

        // ---- scan TC steps, 1 barrier each (double-buffered h)
        f32x4 xwn = *(const f32x4*)&xwc4[cq][0][0];
        for (int ts = 0; ts < TC; ++ts) {
            const f16* hp = &hbuf[cur][0];
            // post-barrier: 6 broadcast ds_read_b128 (slots 2..7 only;
            // slots 0,1 already in hpre0/hpre1 from the pre-barrier reads)
            f16x8 h2 = *(const f16x8*)(hp + oh2);
            f16x8 h3 = *(const f16x8*)(hp + oh3);
            f16x8 h4 = *(const f16x8*)(hp + oh4);
            f16x8 h5 = *(const f16x8*)(hp + oh5);
            f16x8 h6 = *(const f16x8*)(hp + oh6);
            f16x8 h7 = *(const f16x8*)(hp + oh7);

            // this step's xw select (off critical path), then prefetch next
            float x01   = (grp & 1) ? xwn[1] : xwn[0];
            float x23   = (grp & 1) ? xwn[3] : xwn[2];
            float xwsel = (grp & 2) ? x23 : x01;
            xwn = *(const f32x4*)&xwc4[cq][ts + 1][0];   // row 32 = pad, discarded

            // chains: A = slots 0-3 (0,1 in registers -> pipe starts at
            // barrier-exit), B = slots 4-7. Zero-seeded, combine at end.
            const f32x4 z = {0.f, 0.f, 0.f, 0.f};
            f32x4 a0A = MFMA16(hpre0, wfh[0][0], z);
            f32x4 a1A = MFMA16(hpre0, wfh[1][0], z);
            f32x4 a2A = MFMA16(hpre0, wfh[2][0], z);
            f32x4 a3A = MFMA16(hpre0, wfh[3][0], z);

            a0A = MFMA16(hpre1, wfh[0][1], a0A);
            a1A = MFMA16(hpre1, wfh[1][1], a1A);
            a2A = MFMA16(hpre1, wfh[2][1], a2A);
            a3A = MFMA16(hpre1, wfh[3][1], a3A);

            f32x4 a0B = MFMA16(h4, wfh[0][4], z);
            f32x4 a1B = MFMA16(h4, wfh[1][4], z);
            f32x4 a2B = MFMA16(h4, wfh[2][4], z);
            f32x4 a3B = MFMA16(h4, wfh[3][4], z);

            a0A = MFMA16(h2, wfh[0][2], a0A);
            a1A = MFMA16(h2, wfh[1][2], a1A);
            a2A = MFMA16(h2, wfh[2][2], a2A);
            a3A = MFMA16(h2, wfh[3][2], a3A);

            a0B = MFMA16(h5, wfh[0][5], a0B);
            a1B = MFMA16(h5, wfh[1][5], a1B);
            a2B = MFMA16(h5, wfh[2][5], a2B);
            a3B = MFMA16(h5, wfh[3][5], a3B);

            a0A = MFMA16(h3, wfh[0][3], a0A);
            a1A = MFMA16(h3, wfh[1][3], a1A);
            a2A = MFMA16(h3, wfh[2][3], a2A);
            a3A = MFMA16(h3, wfh[3][3], a3A);

            a0B = MFMA16(h6, wfh[0][6], a0B);
            a1B = MFMA16(h6, wfh[1][6], a1B);
            a2B = MFMA16(h6, wfh[2][6], a2B);
            a3B = MFMA16(h6, wfh[3][6], a3B);

            a0B = MFMA16(h7, wfh[0][7], a0B);
            a1B = MFMA16(h7, wfh[1][7], a1B);
            a2B = MFMA16(h7, wfh[2][7], a2B);
            a3B = MFMA16(h7, wfh[3][7], a3B);

            // this lane owns tile (grp): col = wbase + grp*16 + l15 = wbase+lane
            float sA01 = (grp & 1) ? a1A[0] : a0A[0];
            float sA23 = (grp & 1) ? a3A[0] : a2A[0];
            float sA   = (grp & 2) ? sA23 : sA01;
            float sB01 = (grp & 1) ? a1B[0] : a0B[0];
            float sB23 = (grp & 1) ? a3B[0] : a2B[0];
            float sB   = (grp & 2) ? sB23 : sB01;
            float s    = (sA + sB) + xwsel;

            float e   = __expf(2.f * s);
            float th  = 1.f - __fdividef(2.f, e + 1.f);
            th_keep = th;
            f16* hnx = &hbuf[cur ^ 1][0];
            hnx[wbase + lane] = (f16)th;          // ds_write (must precede barrier)

            // pre-read own slices for NEXT step; these two reads stay in
            // flight across the barrier (SCAN_BARRIER waits lgkmcnt(2):
            // in-order LDS => the older write IS complete; reads aren't).
            hpre0 = *(const f16x8*)(hnx + own0);
            hpre1 = *(const f16x8*)(hnx + own1);

            SCAN_BARRIER();
            cur ^= 1;
        }
    }

    // th_keep's col = wbase + lane -> coalesced store
    out[(size_t)b * Hv + wbase + lane] = th_keep;
}

extern "C" void kernel_launch(void* const* d_in, const int* in_sizes, int n_in,
                              void* d_out, int out_size, void* d_ws, size_t ws_size,
                              hipStream_t stream) {
    const float* x    = (const float*)d_in[0];   // [B,T,H]
    const float* wx   = (const float*)d_in[1];   // [H,H]
    const float* wh   = (const float*)d_in[2];   // [H,H]
    const float* bias = (const float*)d_in[3];   // [1,H]
    float* out = (float*)d_out;                  // [B,1,H]

    hipLaunchKernelGGL(HiddenLayer_704374636647_kernel,
                       dim3(Bv), dim3(256), 0, stream,
                       x, wx, wh, bias, out);
}

// Round 12
// 921.110 us; speedup vs baseline: 1.4698x; 1.2248x over previous
//
#include <hip/hip_runtime.h>
#include <math.h>

// Vanilla RNN: h_t = tanh(h_{t-1} @ wh + x_t @ wx + b), out = h_T  [B,1,H]
// B=256, T=2048, H=256, fp32 in/out.
//
// Round 11 = round 5 (911us champion) + removal of the GEMM->scan barrier
// (xwc4[cq][*] is written and read by the SAME wave; per-wave LDS ops are
// in-order, so the RAW is safe without a barrier — validated in r9).
//
// r5 design (final structure):
//  - 256 blocks (1 batch row/CU) x 256 threads (4 waves, 1/SIMD).
//    Wall time = per-step serial latency; all 256 rows run concurrently.
//  - Recurrence via replicated-row MFMA: A-frag carries h broadcast into all
//    16 M-rows -> every lane holds the full column sum in acc reg0; no
//    cross-lane reduction. 128 MFMA/CU/step = 620cy pipe floor.
//  - wh AND wx B-frags resident in registers (1 wave/SIMD -> 512 VGPR).
//  - k-split=2: two independent 4-deep MFMA chains per column tile.
//  - Chunk GEMM (xw = x@wx + b) runs serially between chunks; xw-seed
//    prefetched one step ahead; h double-buffered; ONE raw s_barrier/step
//    (lgkmcnt(0) only — vmcnt stays in flight across the scan).
//
// Post-mortem ledger (why this structure is the plateau):
//  r6 (GEMM interleaved into scan): 1197us — schedule blowup. r7/r8 (shfl
//  own-slice regs): 1354us — __shfl IS a DS op. r9 (pre-read, full drain):
//  1162us — write->read serialization. r10 (pre-read, counted lgkmcnt(2)):
//  1128us — compiler emits conservative lgkmcnt(0) after asm barrier.
//  Fill (~120cy), pipe (620cy), serial tail (~210cy), GEMM (~45cy) are each
//  structural or compiler-locked at HIP source level.

typedef _Float16 f16;
typedef _Float16 f16x4 __attribute__((ext_vector_type(4)));
typedef _Float16 f16x8 __attribute__((ext_vector_type(8)));
typedef float    f32x4 __attribute__((ext_vector_type(4)));

#define Bv 256
#define Tv 2048
#define Hv 256
#define TC 32
#define NCHUNK (Tv/TC)
#define XS_LD 264          // f16 row stride (528B -> 2-way banks, free)
#define XW_TS (TC+1)       // ts-dim pad: row ts+1 always readable (incl. ts=31)

#define LGKM_BARRIER() do { \
    asm volatile("s_waitcnt lgkmcnt(0)" ::: "memory"); \
    __builtin_amdgcn_s_barrier(); \
} while (0)

#define MFMA16(a, b, c) __builtin_amdgcn_mfma_f32_16x16x32_f16((a), (b), (c), 0, 0, 0)

__device__ __forceinline__ f16x4 cvt4(float4 v) {
    f16x4 r; r[0] = (f16)v.x; r[1] = (f16)v.y; r[2] = (f16)v.z; r[3] = (f16)v.w;
    return r;
}

__global__ __launch_bounds__(256, 1)
void HiddenLayer_704374636647_kernel(const float* __restrict__ x,
                                     const float* __restrict__ wx,
                                     const float* __restrict__ wh,
                                     const float* __restrict__ bias,
                                     float* __restrict__ out)
{
    __shared__ __align__(16) f16   xs16[TC][XS_LD];     // 16.9 KB
    __shared__ __align__(16) float xwc4[64][XW_TS][4];  // 33.8 KB
    __shared__ __align__(16) f16   hbuf[2][Hv];         //  1.0 KB

    const int  tid   = threadIdx.x;       // 0..255
    const int  wave  = tid >> 6;          // 0..3
    const int  lane  = tid & 63;
    const int  b     = blockIdx.x;
    const int  wbase = wave * 64;         // 64-col slice owned by wave
    const int  l15   = lane & 15;
    const int  grp   = lane >> 4;         // 0..3
    const int  cq    = wave * 16 + l15;   // xwc4 column-quad index
    const int  koff  = grp * 8;           // A-frag k-offset

    const float* xb = x + (size_t)b * Tv * Hv;

    // ---- global x prefetch: 8 rows (wave + 4s) x 4 f32/lane
    float4 xr0, xr1, xr2, xr3, xr4, xr5, xr6, xr7;
#define LOADX(cc) do { const float* p_ = xb + ((size_t)(cc) * TC + wave) * Hv + lane * 4; \
    xr0 = *(const float4*)(p_);           xr1 = *(const float4*)(p_ +  4 * Hv); \
    xr2 = *(const float4*)(p_ +  8 * Hv); xr3 = *(const float4*)(p_ + 12 * Hv); \
    xr4 = *(const float4*)(p_ + 16 * Hv); xr5 = *(const float4*)(p_ + 20 * Hv); \
    xr6 = *(const float4*)(p_ + 24 * Hv); xr7 = *(const float4*)(p_ + 28 * Hv); } while (0)

    LOADX(0);

    // ---- weight B-frags: tile t covers col wbase + t*16 + l15; k = kt*32 + koff + e
    f16x8 wfh[4][8];   // wh (recurrence), 128 VGPR
    f16x8 wfx[4][8];   // wx (projection), 128 VGPR
    #pragma unroll
    for (int t = 0; t < 4; ++t) {
        #pragma unroll
        for (int kt = 0; kt < 8; ++kt) {
            const float* ph = wh + (size_t)(kt * 32 + koff) * Hv + wbase + t * 16 + l15;
            const float* pw = wx + (size_t)(kt * 32 + koff) * Hv + wbase + t * 16 + l15;
            f16x8 vh, vw;
            #pragma unroll
            for (int e = 0; e < 8; ++e) {
                vh[e] = (f16)ph[(size_t)e * Hv];
                vw[e] = (f16)pw[(size_t)e * Hv];
            }
            wfh[t][kt] = vh;
            wfx[t][kt] = vw;
        }
    }

    const float bc0 = bias[wbase + l15];
    const float bc1 = bias[wbase + 16 + l15];
    const float bc2 = bias[wbase + 32 + l15];
    const float bc3 = bias[wbase + 48 + l15];

    hbuf[0][tid] = (f16)0.0f;   // h_0 = 0 (256 threads cover 256)

    int   cur     = 0;
    float th_keep = 0.0f;

    #pragma unroll 1
    for (int c = 0; c < NCHUNK; ++c) {
        // ---- stage prefetched x (f32->f16): row wave+4s, cols lane*4..+3
        *(f16x4*)&xs16[wave     ][lane * 4] = cvt4(xr0);
        *(f16x4*)&xs16[wave +  4][lane * 4] = cvt4(xr1);
        *(f16x4*)&xs16[wave +  8][lane * 4] = cvt4(xr2);
        *(f16x4*)&xs16[wave + 12][lane * 4] = cvt4(xr3);
        *(f16x4*)&xs16[wave + 16][lane * 4] = cvt4(xr4);
        *(f16x4*)&xs16[wave + 20][lane * 4] = cvt4(xr5);
        *(f16x4*)&xs16[wave + 24][lane * 4] = cvt4(xr6);
        *(f16x4*)&xs16[wave + 28][lane * 4] = cvt4(xr7);

        if (c + 1 < NCHUNK) LOADX(c + 1);   // in flight across GEMM + scan

        LGKM_BARRIER();   // xs16 visible (and hbuf zeros at c==0)

        // ---- chunk GEMM: xwc4 = xs16 @ wx + bias (per wave: its 64 cols)
        {
            f32x4 gA0 = {bc0,bc0,bc0,bc0}, gA1 = {bc1,bc1,bc1,bc1};
            f32x4 gA2 = {bc2,bc2,bc2,bc2}, gA3 = {bc3,bc3,bc3,bc3};
            f32x4 gB0 = gA0, gB1 = gA1, gB2 = gA2, gB3 = gA3;
            #pragma unroll
            for (int kt = 0; kt < 8; ++kt) {
                f16x8 u0 = *(const f16x8*)&xs16[l15     ][kt * 32 + koff];
                f16x8 u1 = *(const f16x8*)&xs16[l15 + 16][kt * 32 + koff];
                gA0 = MFMA16(u0, wfx[0][kt], gA0);
                gA1 = MFMA16(u0, wfx[1][kt], gA1);
                gA2 = MFMA16(u0, wfx[2][kt], gA2);
                gA3 = MFMA16(u0, wfx[3][kt], gA3);
                gB0 = MFMA16(u1, wfx[0][kt], gB0);
                gB1 = MFMA16(u1, wfx[1][kt], gB1);
                gB2 = MFMA16(u1, wfx[2][kt], gB2);
                gB3 = MFMA16(u1, wfx[3][kt], gB3);
            }
            // D: row(ts) = grp*4 + r, col = l15 -> write [cq][ts] as 4-col quad
            #pragma unroll
            for (int r = 0; r < 4; ++r) {
                f32x4 v = {gA0[r], gA1[r], gA2[r], gA3[r]};
                *(f32x4*)&xwc4[cq][grp * 4 + r][0] = v;
                f32x4 w = {gB0[r], gB1[r], gB2[r], gB3[r]};
                *(f32x4*)&xwc4[cq][16 + grp * 4 + r][0] = w;
            }
        }

        // NO barrier: xwc4[cq][*] rows are all written by this wave's lanes
        // (same cq, grp 0..3) and read only by this wave's lanes -> wave-local
        // RAW, safe under per-wave in-order LDS. (Validated in r9.)

        // ---- scan TC steps, 1 barrier each (double-buffered h)
        f32x4 xwn = *(const f32x4*)&xwc4[cq][0][0];
        for (int ts = 0; ts < TC; ++ts) {
            const f16* hp = &hbuf[cur][0];
            // issue all h-frag reads first (broadcast, conflict-free)
            f16x8 ha0 = *(const f16x8*)(hp + koff);
            f16x8 ha1 = *(const f16x8*)(hp + koff + 32);
            f16x8 ha2 = *(const f16x8*)(hp + koff + 64);
            f16x8 ha3 = *(const f16x8*)(hp + koff + 96);
            f16x8 ha4 = *(const f16x8*)(hp + koff + 128);
            f16x8 ha5 = *(const f16x8*)(hp + koff + 160);
            f16x8 ha6 = *(const f16x8*)(hp + koff + 192);
            f16x8 ha7 = *(const f16x8*)(hp + koff + 224);

            // this step's xw select (off critical path), then prefetch next
            float x01   = (grp & 1) ? xwn[1] : xwn[0];
            float x23   = (grp & 1) ? xwn[3] : xwn[2];
            float xwsel = (grp & 2) ? x23 : x01;
            xwn = *(const f32x4*)&xwc4[cq][ts + 1][0];   // row 32 = pad, discarded

            // k-split=2: two independent 4-deep chains per tile, zero-seeded
            const f32x4 z = {0.f, 0.f, 0.f, 0.f};
            f32x4 a0A = MFMA16(ha0, wfh[0][0], z), a0B = MFMA16(ha4, wfh[0][4], z);
            f32x4 a1A = MFMA16(ha0, wfh[1][0], z), a1B = MFMA16(ha4, wfh[1][4], z);
            f32x4 a2A = MFMA16(ha0, wfh[2][0], z), a2B = MFMA16(ha4, wfh[2][4], z);
            f32x4 a3A = MFMA16(ha0, wfh[3][0], z), a3B = MFMA16(ha4, wfh[3][4], z);

            a0A = MFMA16(ha1, wfh[0][1], a0A);  a0B = MFMA16(ha5, wfh[0][5], a0B);
            a1A = MFMA16(ha1, wfh[1][1], a1A);  a1B = MFMA16(ha5, wfh[1][5], a1B);
            a2A = MFMA16(ha1, wfh[2][1], a2A);  a2B = MFMA16(ha5, wfh[2][5], a2B);
            a3A = MFMA16(ha1, wfh[3][1], a3A);  a3B = MFMA16(ha5, wfh[3][5], a3B);

            a0A = MFMA16(ha2, wfh[0][2], a0A);  a0B = MFMA16(ha6, wfh[0][6], a0B);
            a1A = MFMA16(ha2, wfh[1][2], a1A);  a1B = MFMA16(ha6, wfh[1][6], a1B);
            a2A = MFMA16(ha2, wfh[2][2], a2A);  a2B = MFMA16(ha6, wfh[2][6], a2B);
            a3A = MFMA16(ha2, wfh[3][2], a3A);  a3B = MFMA16(ha6, wfh[3][6], a3B);

            a0A = MFMA16(ha3, wfh[0][3], a0A);  a0B = MFMA16(ha7, wfh[0][7], a0B);
            a1A = MFMA16(ha3, wfh[1][3], a1A);  a1B = MFMA16(ha7, wfh[1][7], a1B);
            a2A = MFMA16(ha3, wfh[2][3], a2A);  a2B = MFMA16(ha7, wfh[2][7], a2B);
            a3A = MFMA16(ha3, wfh[3][3], a3A);  a3B = MFMA16(ha7, wfh[3][7], a3B);

            // this lane owns tile (grp): col = wbase + grp*16 + l15 = wbase+lane
            float sA01 = (grp & 1) ? a1A[0] : a0A[0];
            float sA23 = (grp & 1) ? a3A[0] : a2A[0];
            float sA   = (grp & 2) ? sA23 : sA01;
            float sB01 = (grp & 1) ? a1B[0] : a0B[0];
            float sB23 = (grp & 1) ? a3B[0] : a2B[0];
            float sB   = (grp & 2) ? sB23 : sB01;
            float s    = (sA + sB) + xwsel;

            float e   = __expf(2.f * s);
            float th  = 1.f - __fdividef(2.f, e + 1.f);
            th_keep = th;
            hbuf[cur ^ 1][wbase + lane] = (f16)th;
            LGKM_BARRIER();
            cur ^= 1;
        }
    }

    // th_keep's col = wbase + lane -> coalesced store
    out[(size_t)b * Hv + wbase + lane] = th_keep;
}

extern "C" void kernel_launch(void* const* d_in, const int* in_sizes, int n_in,
                              void* d_out, int out_size, void* d_ws, size_t ws_size,
                              hipStream_t stream) {
    const float* x    = (const float*)d_in[0];   // [B,T,H]
    const float* wx   = (const float*)d_in[1];   // [H,H]
    const float* wh   = (const float*)d_in[2];   // [H,H]
    const float* bias = (const float*)d_in[3];   // [1,H]
    float* out = (float*)d_out;                  // [B,1,H]

    hipLaunchKernelGGL(HiddenLayer_704374636647_kernel,
                       dim3(Bv), dim3(256), 0, stream,
                       x, wx, wh, bias, out);
}